// Round 2
// baseline (57.545 us; speedup 1.0000x reference)
//
#include <hip/hip_runtime.h>

// Problem constants (B=131072 rows, C=64 cols)
#define NROWS 131072
#define NCOLS 64
#define NBLK_A 512
#define THREADS_A 512        // 8 waves per block
#define WAVES_A (THREADS_A / 64)
#define ROWS_PER_WAVE 32     // 512 blocks * 8 waves * 32 rows = 131072
#define NGROUPS 16           // B1 reduction groups (32 blocks each)
#define PK_CELLS 4096        // packed u16-pair cells per block (2048 S + 2048 P)

// -------- Kernel A: fused focal loss + Gram (S = t^T t, P = v^T w) --------
// Layout: lane l loads float4 -> columns c4=4*(l&15)..c4+3 of rows r0+(l>>4)+4q.
// Per-column 32-row bitmasks are built with disjoint bit positions (bit = 4q+h)
// and OR-combined across the 4 row-phases via shfl_xor(16|32); lane then owns
// the mask of column jc = c4 + h (a permutation of 0..63).
// Gram: 64-iter readlane loop with compile-time inverse-permutation lane index,
// byte-packed accumulators (counts <= 32). Block reduce: u16-pair LDS atomics
// (counts <= 8*32=256). Flush: per-block packed partial, or global atomics.
template<bool ATOMIC_FLUSH>
__global__ __launch_bounds__(THREADS_A, 4)
void kernA(const float* __restrict__ in, const float* __restrict__ tg,
           const float* __restrict__ pw, double* __restrict__ focal_acc,
           unsigned* __restrict__ pk,           // partial path: pk[block][4096]
           unsigned* __restrict__ gS,           // atomic path: S cells u32[4096]
           unsigned* __restrict__ gP) {         // atomic path: P cells u32[4096]
    __shared__ unsigned ldsSP[PK_CELLS];  // [0..2047]=S packed, [2048..4095]=P packed
    __shared__ float fpart[WAVES_A];
    const int tid = threadIdx.x;
#pragma unroll
    for (int k = tid; k < PK_CELLS; k += THREADS_A) ldsSP[k] = 0u;
    __syncthreads();

    const int lane = tid & 63;
    const int wv = tid >> 6;                 // 0..7
    const int h = lane >> 4;                 // row phase 0..3
    const int c4 = (lane & 15) * 4;          // first of this lane's 4 columns
    const int row0 = blockIdx.x * (WAVES_A * ROWS_PER_WAVE) + wv * ROWS_PER_WAVE;

    const float4 pw4 = *reinterpret_cast<const float4*>(pw + c4);
    const float4* inp = reinterpret_cast<const float4*>(in + (size_t)(row0 + h) * NCOLS + c4);
    const float4* tgp = reinterpret_cast<const float4*>(tg + (size_t)(row0 + h) * NCOLS + c4);
    const unsigned hbit = 1u << h;

    float fsum = 0.f;
    unsigned m4[4] = {0u, 0u, 0u, 0u};
    unsigned v4[4] = {0u, 0u, 0u, 0u};

    auto elem = [&](float x, float t, float pwc, unsigned hq, unsigned& mk, unsigned& vk) {
        float ax = fabsf(x);
        float e = __expf(-ax);               // exp(-|x|)
        float L = __logf(1.f + e);           // log1p(exp(-|x|)), stable
        float inv = 1.f / (1.f + e);         // sigmoid(|x|)
        float qq = e * inv;                  // 1 - sigmoid(|x|)
        bool tb = t > 0.5f;
        bool pb = x >= 0.f;
        float w = (tb == pb) ? qq : inv;     // 1 - p_t
        float bce = tb ? pwc * (L + fmaxf(-x, 0.f)) : (L + fmaxf(x, 0.f));
        fsum += w * w * bce;
        mk |= tb ? hq : 0u;
        vk |= (tb && pb) ? hq : 0u;
    };

#pragma unroll
    for (int q = 0; q < 8; ++q) {            // rows r0 + h + 4q
        const float4 xv = inp[(size_t)q * 64];   // stride 4 rows = 64 float4
        const float4 tv = tgp[(size_t)q * 64];
        const unsigned hq = hbit << (4 * q); // disjoint bit position 4q+h
        elem(xv.x, tv.x, pw4.x, hq, m4[0], v4[0]);
        elem(xv.y, tv.y, pw4.y, hq, m4[1], v4[1]);
        elem(xv.z, tv.z, pw4.z, hq, m4[2], v4[2]);
        elem(xv.w, tv.w, pw4.w, hq, m4[3], v4[3]);
    }

    // OR-combine the 4 row-phases; bit b of the result = row r0+b for that column
#pragma unroll
    for (int k = 0; k < 4; ++k) {
        m4[k] |= __shfl_xor(m4[k], 16, 64);
        m4[k] |= __shfl_xor(m4[k], 32, 64);
        v4[k] |= __shfl_xor(v4[k], 16, 64);
        v4[k] |= __shfl_xor(v4[k], 32, 64);
    }
    // lane keeps the mask for column jc = c4 + h
    const unsigned m = (h & 2) ? ((h & 1) ? m4[3] : m4[2]) : ((h & 1) ? m4[1] : m4[0]);
    const unsigned v = (h & 2) ? ((h & 1) ? v4[3] : v4[2]) : ((h & 1) ? v4[1] : v4[0]);
    const unsigned wm = m & ~v;              // t=1, pred=0

    unsigned accS[16], accP[16];
#pragma unroll
    for (int k = 0; k < 16; ++k) { accS[k] = 0u; accP[k] = 0u; }
    // column a lives in lane ri = ((a&3)<<4) | (a>>2)  (inverse of jc(l))
#pragma unroll
    for (int a = 0; a < 64; ++a) {
        const int ri = ((a & 3) << 4) | (a >> 2);
        unsigned mi = (unsigned)__builtin_amdgcn_readlane((int)m, ri);
        unsigned vi = (unsigned)__builtin_amdgcn_readlane((int)v, ri);
        accS[a >> 2] += (unsigned)__popc(mi & m)  << (8 * (a & 3));  // S[a][jc]
        accP[a >> 2] += (unsigned)__popc(vi & wm) << (8 * (a & 3));  // P[a][jc]
    }

    // LDS reduce across the 8 waves (u16-pair packed; max 8*32=256 < 65536)
    const int jc = c4 + h;
#pragma unroll
    for (int k = 0; k < 16; ++k) {
        unsigned aS = accS[k], aP = accP[k];
        atomicAdd(&ldsSP[(2 * k + 0) * 64 + jc],
                  (aS & 0xFFu) | (((aS >> 8) & 0xFFu) << 16));
        atomicAdd(&ldsSP[(2 * k + 1) * 64 + jc],
                  ((aS >> 16) & 0xFFu) | (((aS >> 24) & 0xFFu) << 16));
        atomicAdd(&ldsSP[2048 + (2 * k + 0) * 64 + jc],
                  (aP & 0xFFu) | (((aP >> 8) & 0xFFu) << 16));
        atomicAdd(&ldsSP[2048 + (2 * k + 1) * 64 + jc],
                  ((aP >> 16) & 0xFFu) | (((aP >> 24) & 0xFFu) << 16));
    }

    // focal: wave reduce then block reduce
#pragma unroll
    for (int off = 32; off; off >>= 1) fsum += __shfl_down(fsum, off, 64);
    if (lane == 0) fpart[wv] = fsum;
    __syncthreads();

    if (tid == 0) {
        float tot = 0.f;
#pragma unroll
        for (int k = 0; k < WAVES_A; ++k) tot += fpart[k];
        atomicAdd(focal_acc, (double)tot);
    }

    if (!ATOMIC_FLUSH) {
        uint4* dst4 = reinterpret_cast<uint4*>(pk + (size_t)blockIdx.x * PK_CELLS);
        const uint4* src4 = reinterpret_cast<const uint4*>(ldsSP);
#pragma unroll
        for (int k = tid; k < PK_CELLS / 4; k += THREADS_A) dst4[k] = src4[k];
    } else {
        for (int k = tid; k < 2048; k += THREADS_A) {
            int ip = k >> 6, j = k & 63;
            unsigned s = ldsSP[k], p = ldsSP[2048 + k];
            atomicAdd(&gS[(2 * ip + 0) * 64 + j], s & 0xFFFFu);
            atomicAdd(&gS[(2 * ip + 1) * 64 + j], s >> 16);
            atomicAdd(&gP[(2 * ip + 0) * 64 + j], p & 0xFFFFu);
            atomicAdd(&gP[(2 * ip + 1) * 64 + j], p >> 16);
        }
    }
}

// -------- B1: reduce 512 block-partials into 16 unpacked group sums --------
__global__ void kernB1(const unsigned* __restrict__ pk, unsigned* __restrict__ red) {
    int t = blockIdx.x * 256 + threadIdx.x;   // 0..65535 = 16 groups x 4096 cells
    int g = t >> 12;
    int pc = t & 4095;
    unsigned lo = 0u, hi = 0u;
    const unsigned* p = pk + (size_t)(g * 32) * PK_CELLS + pc;
#pragma unroll 8
    for (int b = 0; b < 32; ++b) {
        unsigned val = p[(size_t)b * PK_CELLS];
        lo += val & 0xFFFFu;
        hi += val >> 16;
    }
    int mat = pc >> 11;                // 0=S, 1=P
    int e = pc & 2047;
    int ip = e >> 6, j = e & 63;       // word (2k+d) -> rows 2*ip, 2*ip+1
    unsigned* out = red + (size_t)g * 8192 + mat * 4096;
    out[(2 * ip + 0) * 64 + j] = lo;
    out[(2 * ip + 1) * 64 + j] = hi;
}

// -------- B2: finish S,P; penalty = sum_{i!=j, corr>thr} corr_ij * P_ij ----
__global__ void kernB2(const unsigned* __restrict__ red, double* __restrict__ pen_acc) {
    int c = blockIdx.x * 256 + threadIdx.x;   // 0..4095 cell (i,j)
    unsigned S = 0u, P = 0u;
#pragma unroll
    for (int g = 0; g < NGROUPS; ++g) {
        S += red[g * 8192 + c];
        P += red[g * 8192 + 4096 + c];
    }
    int i = c >> 6, j = c & 63;
    float corr = (float)S * (1.0f / (float)NROWS);
    // penalty_total = 2 * sum A_ij * P_ij, A = 0.5*corr (thresholded) => corr*P
    double contrib = (i != j && corr > 0.3f) ? (double)corr * (double)P : 0.0;
#pragma unroll
    for (int off = 32; off; off >>= 1) contrib += __shfl_down(contrib, off, 64);
    __shared__ double dpart[4];
    int lane = threadIdx.x & 63, wv = threadIdx.x >> 6;
    if (lane == 0) dpart[wv] = contrib;
    __syncthreads();
    if (threadIdx.x == 0)
        atomicAdd(pen_acc, dpart[0] + dpart[1] + dpart[2] + dpart[3]);
}

// B2 variant for the atomic-fallback path (reads final S,P directly)
__global__ void kernB2d(const unsigned* __restrict__ gS, const unsigned* __restrict__ gP,
                        double* __restrict__ pen_acc) {
    int c = blockIdx.x * 256 + threadIdx.x;
    unsigned S = gS[c], P = gP[c];
    int i = c >> 6, j = c & 63;
    float corr = (float)S * (1.0f / (float)NROWS);
    double contrib = (i != j && corr > 0.3f) ? (double)corr * (double)P : 0.0;
#pragma unroll
    for (int off = 32; off; off >>= 1) contrib += __shfl_down(contrib, off, 64);
    __shared__ double dpart[4];
    int lane = threadIdx.x & 63, wv = threadIdx.x >> 6;
    if (lane == 0) dpart[wv] = contrib;
    __syncthreads();
    if (threadIdx.x == 0)
        atomicAdd(pen_acc, dpart[0] + dpart[1] + dpart[2] + dpart[3]);
}

// -------- C: finalize --------
__global__ void kernC(const double* __restrict__ focal, const double* __restrict__ pen,
                      float* __restrict__ out) {
    out[0] = (float)((focal[0] + pen[0]) * (1.0 / (double)((size_t)NROWS * NCOLS)));
}

extern "C" void kernel_launch(void* const* d_in, const int* in_sizes, int n_in,
                              void* d_out, int out_size, void* d_ws, size_t ws_size,
                              hipStream_t stream) {
    const float* in = (const float*)d_in[0];
    const float* tg = (const float*)d_in[1];
    const float* pw = (const float*)d_in[2];
    float* out = (float*)d_out;
    char* ws = (char*)d_ws;
    double* focal = (double*)ws;
    double* pen = (double*)(ws + 8);

    const size_t pk_bytes = (size_t)NBLK_A * PK_CELLS * sizeof(unsigned);   // 8 MB
    const size_t red_bytes = (size_t)NGROUPS * 8192 * sizeof(unsigned);     // 512 KB
    const size_t need = 64 + pk_bytes + red_bytes;

    hipMemsetAsync(ws, 0, 64, stream);  // zero focal_acc, pen_acc

    if (ws_size >= need) {
        unsigned* pk = (unsigned*)(ws + 64);
        unsigned* red = (unsigned*)(ws + 64 + pk_bytes);
        kernA<false><<<NBLK_A, THREADS_A, 0, stream>>>(in, tg, pw, focal, pk, nullptr, nullptr);
        kernB1<<<(NGROUPS * PK_CELLS) / 256, 256, 0, stream>>>(pk, red);
        kernB2<<<16, 256, 0, stream>>>(red, pen);
    } else {
        // fallback: needs only 64 + 32 KB of workspace
        unsigned* gS = (unsigned*)(ws + 64);
        unsigned* gP = gS + 4096;
        hipMemsetAsync(ws + 64, 0, 8192 * sizeof(unsigned), stream);
        kernA<true><<<NBLK_A, THREADS_A, 0, stream>>>(in, tg, pw, focal, nullptr, gS, gP);
        kernB2d<<<16, 256, 0, stream>>>(gS, gP, pen);
    }
    kernC<<<1, 1, 0, stream>>>(focal, pen, out);
}